// Round 7
// baseline (536.620 us; speedup 1.0000x reference)
//
#include <hip/hip_runtime.h>
#include <hip/hip_fp16.h>
#include <type_traits>

// MultiHeadRelativeAttention (B=4, S=2048, H=8, dh=64, MAX_REL=96)
// K0a: proj = Q @ relk^T as f16 MFMA GEMM -> gproj
// K0b: Wo -> f16
// K0c: relv -> pre-packed MFMA B-frags (h16), zero-padded to 224 bins
// K1 : fused rel-pos flash attention, 3 blocks/CU (50.2 KB LDS):
//      - K B-frags straight from global (no LDS staging)
//      - attnR bins in h16, plain RMW (provably race-free: rv injective per
//        16 consecutive k within a 64-aligned tile; rows wave-owned)
//      - pure-clip tile classification (R5, validated)
//      - w2 epilogue as 7x4 MFMAs vs pre-packed relv frags
// K2 : x @ Wo^T + bo (f16 MFMA)

#define SEQ   2048
#define NHEAD 8
#define DH    64
#define HID   512
#define ROWW  1536   // qkv row stride in floats (3*512)
#define QT    64
#define GPS   196    // gproj row stride (193 bins, padded)

#define C_L2E8 0.180336880111120f   // 0.125 * log2(e): softmax scale folded into exp2

typedef _Float16 h16;
typedef __attribute__((ext_vector_type(4))) float    f32x4;
typedef __attribute__((ext_vector_type(8))) _Float16 h16x8;
typedef __attribute__((ext_vector_type(4))) _Float16 h16x4;

static __device__ __forceinline__ h16x8 pack8(float4 a, float4 b) {
  h16x8 r;
  r[0]=(h16)a.x; r[1]=(h16)a.y; r[2]=(h16)a.z; r[3]=(h16)a.w;
  r[4]=(h16)b.x; r[5]=(h16)b.y; r[6]=(h16)b.z; r[7]=(h16)b.w;
  return r;
}

// LDS. attnRh stride 232 h16 (464 B, 16B-aligned; 116 dw = 20 mod 32 -> 2-way max
// on epilogue A-frag reads). Vt stride 72 + 3-bit XOR swizzle (validated). P stride
// 88 h16 (176 B; 44 dw = 12 mod 32 -> 2-way reads, 2-way writes).
struct alignas(16) SmBase {
  h16 attnRh[64][232];   // 29696 B  per-q-row bin mass, h16 (cols 0/192 = clip; 193+ zero)
  h16 Vt[64][72];        //  9216 B  V tile transposed [d][k^swz]
  h16 P[4][16][88];      // 11264 B  per-wave P staging (D->A layout)
};                       // 50176 B -> 3 blocks/CU
struct alignas(16) SmFull {
  h16 attnRh[64][232];
  h16 Vt[64][72];
  h16 P[4][16][88];
  h16 projh[64][194];    // fallback: proj in LDS -> 75008 B, 2 blocks/CU
};

// ---------------- K0a: proj = Q @ relk^T (MFMA) ----------------
__global__ __launch_bounds__(256)
void proj_gemm(const float* __restrict__ qkv, const float* __restrict__ relk,
               h16* __restrict__ gproj)
{
  const int qt = blockIdx.x, h = blockIdx.y, b = blockIdx.z;
  const int tid = (int)threadIdx.x;
  const int w = tid >> 6, l = tid & 63, l15 = l & 15, l4 = l >> 4;
  const int q0 = qt * 64;

  const float* qr = qkv + ((size_t)(b*SEQ) + q0 + w*16 + l15) * ROWW + h*DH + l4*8;
  h16x8 aq0 = pack8(*(const float4*)(qr),      *(const float4*)(qr + 4));
  h16x8 aq1 = pack8(*(const float4*)(qr + 32), *(const float4*)(qr + 36));

  h16* orow = gproj + ((size_t)(b*NHEAD + h)*SEQ + q0 + w*16) * GPS;

#pragma unroll
  for (int nt = 0; nt < 13; ++nt) {
    const int n0 = nt * 16;
    const int rc = (n0 + l15 > 192) ? 192 : n0 + l15;   // clamp tail tile
    const float* rkp = relk + rc*DH + l4*8;
    h16x8 b0 = pack8(*(const float4*)(rkp),      *(const float4*)(rkp + 4));
    h16x8 b1 = pack8(*(const float4*)(rkp + 32), *(const float4*)(rkp + 36));
    f32x4 z = {};
    z = __builtin_amdgcn_mfma_f32_16x16x32_f16(aq0, b0, z, 0, 0, 0);
    z = __builtin_amdgcn_mfma_f32_16x16x32_f16(aq1, b1, z, 0, 0, 0);
    if (n0 + l15 < GPS) {
#pragma unroll
      for (int j = 0; j < 4; ++j)
        orow[(size_t)(l4*4 + j)*GPS + n0 + l15] = (h16)z[j];
    }
  }
}

// ---------------- K0b: Wo -> f16 ----------------
__global__ __launch_bounds__(256)
void wo_convert(const float* __restrict__ Wo, h16* __restrict__ Woh)
{
  const size_t i = (size_t)blockIdx.x * 256 + threadIdx.x;
  float4 v = *(const float4*)(Wo + i*4);
  h16x4 o; o[0]=(h16)v.x; o[1]=(h16)v.y; o[2]=(h16)v.z; o[3]=(h16)v.w;
  *(h16x4*)(Woh + i*4) = o;
}

// ---------------- K0c: relv -> pre-packed B-frags ----------------
// 28 blocks = kblk(7) x vc(4), 64 thr. frag element e of lane l:
// B[k=l4*8+e][n=vc*16+l15] = relv[kblk*32+l4*8+e][vc*16+l15], zero for k>=193.
__global__ void relv_pack(const float* __restrict__ relv, h16* __restrict__ relvh)
{
  const int bi = (int)blockIdx.x;
  const int l = (int)threadIdx.x, l15 = l & 15, l4 = l >> 4;
  const int kblk = bi >> 2, vc = bi & 3;
  h16x8 o;
#pragma unroll
  for (int e = 0; e < 8; ++e) {
    const int k = kblk*32 + l4*8 + e;
    o[e] = (k < 193) ? (h16)relv[k*DH + vc*16 + l15] : (h16)0.f;
  }
  *(h16x8*)(relvh + ((size_t)bi*64 + l)*8) = o;
}

// ---------------- K1: fused relative attention ----------------
template<bool GP>
__global__ __launch_bounds__(256, 4)
void attn_fused(const float* __restrict__ qkv,
                const float* __restrict__ relk,
                const float* __restrict__ relv,
                const h16* __restrict__ gproj,
                const h16* __restrict__ relvh,
                h16* __restrict__ xout)
{
  using SM = typename std::conditional<GP, SmBase, SmFull>::type;
  __shared__ SM sm;

  // XCD-chunked swizzle: 1024 wgs, 8 XCDs, 128 contiguous work-ids per XCD.
  const int wg = (int)blockIdx.x;
  const int id = (wg & 7) * 128 + (wg >> 3);
  const int qt = id & 31, h = (id >> 5) & 7, b = id >> 8;

  const int tid = (int)threadIdx.x;
  const int w = tid >> 6, l = tid & 63, l15 = l & 15, l4 = l >> 4;
  const int q0 = qt * QT;
  const int dl = l, kq = w;   // V-staging roles

  const float* qbase = qkv + ((size_t)(b*SEQ) + q0) * ROWW + h*DH;
  const float* kbase = qkv + (size_t)(b*SEQ) * ROWW + HID   + h*DH;
  const float* vbase = qkv + (size_t)(b*SEQ) * ROWW + 2*HID + h*DH;
  const h16* gprow = gproj + ((size_t)(b*NHEAD + h)*SEQ + q0 + w*16) * GPS;

  // zero attnRh (int4 stores; h16 zero == 0x0000)
  {
    int4* az = (int4*)&sm.attnRh[0][0];
#pragma unroll 2
    for (int i = tid; i < (int)(sizeof(sm.attnRh)/16); i += 256)
      az[i] = make_int4(0,0,0,0);
  }

  if constexpr (!GP) {
    const int prow = tid >> 2, psub = tid & 3;
    const float* qrow = qbase + (size_t)prow * ROWW;
    float4 qv[16];
#pragma unroll
    for (int c = 0; c < 16; ++c) qv[c] = *(const float4*)(qrow + c*4);
    for (int r = psub; r < 193; r += 4) {
      const float4* rk = (const float4*)(relk + r*DH);
      float acc1 = 0.f;
#pragma unroll
      for (int c = 0; c < 16; ++c) {
        float4 tt = rk[c];
        acc1 += qv[c].x*tt.x + qv[c].y*tt.y + qv[c].z*tt.z + qv[c].w*tt.w;
      }
      sm.projh[prow][r] = (h16)acc1;
    }
  }

  // Q A-fragments: A[m=l15][k=l4*8+e]
  h16x8 aq0, aq1;
  {
    const float* qr = qbase + (size_t)(w*16 + l15) * ROWW + l4*8;
    aq0 = pack8(*(const float4*)(qr),      *(const float4*)(qr + 4));
    aq1 = pack8(*(const float4*)(qr + 32), *(const float4*)(qr + 36));
  }

  int rvq[4];
#pragma unroll
  for (int j = 0; j < 4; ++j) {
    int qg = q0 + w*16 + l4*4 + j;
    rvq[j] = (qg <= 1024) ? qg : (2048 - qg);
  }

  // wave-level rvq range (rv peaks at 1024; min at endpoints)
  const int qa = q0 + w*16, qb = qa + 15;
  const int rqa = (qa <= 1024) ? qa : 2048 - qa;
  const int rqb = (qb <= 1024) ? qb : 2048 - qb;
  const int rvqmin = rqa < rqb ? rqa : rqb;
  const int rvqmax = (qa <= 1024 && 1024 <= qb) ? 1024 : (rqa > rqb ? rqa : rqb);

  // tile class: 0 = all clip to bin 0, 2 = all clip to bin 192, 1 = mixed
  auto classify = [&](int KT) -> int {
    const int ka = KT*64, kb = ka + 63;
    const int ra = (ka <= 1024) ? ka : 2048 - ka;
    const int rb = (kb <= 1024) ? kb : 2048 - kb;
    const int rmin = ra < rb ? ra : rb;
    const int rmax = (ka <= 1024 && 1024 <= kb) ? 1024 : (ra > rb ? ra : rb);
    if (rmax <= rvqmin - 96) return 0;
    if (rmin >= rvqmax + 96) return 2;
    return 1;
  };

  f32x4 acc[4] = {};
  float lsum[4] = {0.f,0.f,0.f,0.f};
  float c0[4]   = {0.f,0.f,0.f,0.f};
  float c192[4] = {0.f,0.f,0.f,0.f};

  float vreg[4][4];

  auto vIssue = [&](int KT) {
    const int kk = KT * 64;
#pragma unroll
    for (int m = 0; m < 4; ++m)
#pragma unroll
      for (int e = 0; e < 4; ++e)
        vreg[m][e] = vbase[(size_t)(kk + m*16 + kq*4 + e)*ROWW + dl];
  };

  auto vWrite = [&]() {
    const int swz = ((dl >> 3) & 7) << 3;   // 3-bit k-XOR, granule 8 h16
#pragma unroll
    for (int m = 0; m < 4; ++m) {
      h16x4 u; u[0]=(h16)vreg[m][0]; u[1]=(h16)vreg[m][1]; u[2]=(h16)vreg[m][2]; u[3]=(h16)vreg[m][3];
      *(h16x4*)(&sm.Vt[dl][(m*16 + kq*4) ^ swz]) = u;
    }
  };

  // ---- prologue ----
  int cls = classify(0);
  vIssue(0);
  vWrite();
  __syncthreads();   // covers attnRh zeroing, projh (!GP), Vt(0)

  float proj0f[4], proj192f[4], C0e[4], C192e[4];
  if constexpr (GP) {
#pragma unroll
    for (int j = 0; j < 4; ++j) {
      proj0f[j]   = (float)gprow[(size_t)(l4*4 + j)*GPS + 0];
      proj192f[j] = (float)gprow[(size_t)(l4*4 + j)*GPS + 192];
    }
  } else {
#pragma unroll
    for (int j = 0; j < 4; ++j) {
      proj0f[j]   = (float)sm.projh[w*16 + l4*4 + j][0];
      proj192f[j] = (float)sm.projh[w*16 + l4*4 + j][192];
    }
  }
#pragma unroll
  for (int j = 0; j < 4; ++j) {
    C0e[j]   = exp2f(proj0f[j]   * C_L2E8);
    C192e[j] = exp2f(proj192f[j] * C_L2E8);
  }

  for (int kt = 0; kt < 32; ++kt) {
    const int kk = kt * 64;

    // ---- QK^T: K B-frags straight from global (out_proj-validated pattern) ----
    f32x4 sc[4];
#pragma unroll
    for (int ct = 0; ct < 4; ++ct) {
      const float* kr = kbase + (size_t)(kk + ct*16 + l15)*ROWW + l4*8;
      h16x8 kb0 = pack8(*(const float4*)(kr),      *(const float4*)(kr + 4));
      h16x8 kb1 = pack8(*(const float4*)(kr + 32), *(const float4*)(kr + 36));
      f32x4 z = {};
      z = __builtin_amdgcn_mfma_f32_16x16x32_f16(aq0, kb0, z, 0, 0, 0);
      z = __builtin_amdgcn_mfma_f32_16x16x32_f16(aq1, kb1, z, 0, 0, 0);
      sc[ct] = z;
    }

    if (kt < 31) vIssue(kt + 1);   // prefetch next V tile into regs

    // ---- middle: rel-pos add, exp, bin mass, P staging ----
    if (cls == 1) {
#pragma unroll
      for (int ct = 0; ct < 4; ++ct) {
        const int kg = kk + ct*16 + l15;
        const int rvk = (kg <= 1024) ? kg : (2048 - kg);
#pragma unroll
        for (int j = 0; j < 4; ++j) {
          const int rowL = w*16 + l4*4 + j;
          int dd = rvk - rvq[j];
          dd = dd < -96 ? -96 : (dd > 96 ? 96 : dd);
          const int bin = dd + 96;
          float pj;
          if constexpr (GP) {
            pj = (bin == 0) ? proj0f[j]
               : (bin == 192) ? proj192f[j]
               : (float)gprow[(size_t)(l4*4 + j)*GPS + bin];
          } else {
            pj = (float)sm.projh[rowL][bin];
          }
          const float p = exp2f((sc[ct][j] + pj) * C_L2E8);
          lsum[j] += p;
          if (bin == 0)        c0[j]   += p;
          else if (bin == 192) c192[j] += p;
          else {
            // race-free RMW: distinct (row,bin) per lane within each instruction
            h16 old = sm.attnRh[rowL][bin];
            sm.attnRh[rowL][bin] = old + (h16)p;
          }
          sm.P[w][l4*4 + j][ct*16 + l15] = (h16)p;
        }
      }
    } else if (cls == 0) {
#pragma unroll
      for (int ct = 0; ct < 4; ++ct) {
#pragma unroll
        for (int j = 0; j < 4; ++j) {
          const float p = exp2f(sc[ct][j] * C_L2E8) * C0e[j];
          lsum[j] += p;
          c0[j]   += p;
          sm.P[w][l4*4 + j][ct*16 + l15] = (h16)p;
        }
      }
    } else {
#pragma unroll
      for (int ct = 0; ct < 4; ++ct) {
#pragma unroll
        for (int j = 0; j < 4; ++j) {
          const float p = exp2f(sc[ct][j] * C_L2E8) * C192e[j];
          lsum[j] += p;
          c192[j] += p;
          sm.P[w][l4*4 + j][ct*16 + l15] = (h16)p;
        }
      }
    }

    // ---- PV: acc += P V ----
    {
      h16x8 pa0 = *(const h16x8*)(&sm.P[w][l15][l4*8]);
      h16x8 pa1 = *(const h16x8*)(&sm.P[w][l15][32 + l4*8]);
#pragma unroll
      for (int vc = 0; vc < 4; ++vc) {
        const int d = vc*16 + l15;
        const int swr = ((d >> 3) & 7) << 3;
        h16x8 vb0 = *(const h16x8*)(&sm.Vt[d][(l4*8) ^ swr]);
        h16x8 vb1 = *(const h16x8*)(&sm.Vt[d][(32 + l4*8) ^ swr]);
        acc[vc] = __builtin_amdgcn_mfma_f32_16x16x32_f16(pa0, vb0, acc[vc], 0, 0, 0);
        acc[vc] = __builtin_amdgcn_mfma_f32_16x16x32_f16(pa1, vb1, acc[vc], 0, 0, 0);
      }
    }

    __syncthreads();                              // all waves done with Vt(kt)
    if (kt < 31) { vWrite(); cls = classify(kt + 1); }
    __syncthreads();                              // Vt(kt+1) visible
  }

  // ---- fold clip masses + lsum over the 16-lane row group ----
#pragma unroll
  for (int j = 0; j < 4; ++j) {
    for (int mask = 1; mask < 16; mask <<= 1) {
      c0[j]   += __shfl_xor(c0[j],   mask);
      c192[j] += __shfl_xor(c192[j], mask);
      lsum[j] += __shfl_xor(lsum[j], mask);
    }
  }
  if (l15 == 0) {
#pragma unroll
    for (int j = 0; j < 4; ++j) {
      sm.attnRh[w*16 + l4*4 + j][0]   = (h16)c0[j];
      sm.attnRh[w*16 + l4*4 + j][192] = (h16)c192[j];
    }
  }
  // no barrier: attnRh rows are wave-local; LDS ops are in-order per wave

  // ---- w2 epilogue: acc += attnRh @ relv  (7 k-blocks x 4 col-tiles MFMA) ----
#pragma unroll
  for (int kb6 = 0; kb6 < 7; ++kb6) {
    h16x8 pa = *(const h16x8*)(&sm.attnRh[w*16 + l15][kb6*32 + l4*8]);
#pragma unroll
    for (int vc = 0; vc < 4; ++vc) {
      h16x8 bf = *(const h16x8*)(relvh + ((size_t)((kb6*4 + vc)*64 + l))*8);
      acc[vc] = __builtin_amdgcn_mfma_f32_16x16x32_f16(pa, bf, acc[vc], 0, 0, 0);
    }
  }

  // ---- normalize + store x (f16) ----
  float inv[4];
#pragma unroll
  for (int j = 0; j < 4; ++j) inv[j] = 1.f / lsum[j];
#pragma unroll
  for (int vc = 0; vc < 4; ++vc) {
#pragma unroll
    for (int j = 0; j < 4; ++j) {
      const int row16 = l4*4 + j;
      const int col   = vc*16 + l15;
      xout[((size_t)(b*SEQ) + q0 + w*16 + row16) * HID + h*DH + col] =
          (h16)(acc[vc][j] * inv[j]);
    }
  }
}

// ---------------- K2: out = x @ Wo^T + bo ----------------
template<bool WH>
__global__ __launch_bounds__(256)
void out_proj(const h16* __restrict__ xh,
              const float* __restrict__ Wo,
              const h16* __restrict__ Woh,
              const float* __restrict__ bo,
              float* __restrict__ out)
{
  const int tid = (int)threadIdx.x;
  const int w = tid >> 6, l = tid & 63, l15 = l & 15, l4 = l >> 4;
  const int m0 = blockIdx.x * 64 + w * 16;
  const int n0 = blockIdx.y * 64;
  f32x4 acc[4] = {};
  const h16* arow = xh + (size_t)(m0 + l15) * HID + l4*8;
#pragma unroll
  for (int ks = 0; ks < 16; ++ks) {
    h16x8 a = *(const h16x8*)(arow + ks*32);
#pragma unroll
    for (int ct = 0; ct < 4; ++ct) {
      h16x8 bfrag;
      if constexpr (WH) {
        bfrag = *(const h16x8*)(Woh + (size_t)(n0 + ct*16 + l15) * HID + ks*32 + l4*8);
      } else {
        const float* wrow = Wo + (size_t)(n0 + ct*16 + l15) * HID + ks*32 + l4*8;
        bfrag = pack8(*(const float4*)wrow, *(const float4*)(wrow + 4));
      }
      acc[ct] = __builtin_amdgcn_mfma_f32_16x16x32_f16(a, bfrag, acc[ct], 0, 0, 0);
    }
  }
#pragma unroll
  for (int ct = 0; ct < 4; ++ct) {
    const int col = n0 + ct*16 + l15;
    const float bv = bo[col];
#pragma unroll
    for (int j = 0; j < 4; ++j)
      out[(size_t)(m0 + l4*4 + j) * HID + col] = acc[ct][j] + bv;
  }
}

extern "C" void kernel_launch(void* const* d_in, const int* in_sizes, int n_in,
                              void* d_out, int out_size, void* d_ws, size_t ws_size,
                              hipStream_t stream)
{
  const float* qkv  = (const float*)d_in[0];
  const float* relk = (const float*)d_in[1];
  const float* relv = (const float*)d_in[2];
  const float* Wo   = (const float*)d_in[3];
  const float* bo   = (const float*)d_in[4];
  float* out = (float*)d_out;

  const size_t sz_xh    = (size_t)4*SEQ*HID*2;            //  8.39 MB
  const size_t sz_gproj = (size_t)4*NHEAD*SEQ*GPS*2;      // 25.69 MB
  const size_t sz_woh   = (size_t)HID*HID*2;              //  0.52 MB
  const size_t sz_relvh = (size_t)28*64*8*2;              // 28672 B

  h16* xh = (h16*)d_ws;

  const size_t off_gproj = sz_xh;
  const size_t off_woh   = off_gproj + sz_gproj;
  const size_t off_relvh = off_woh + sz_woh;
  const size_t need      = off_relvh + sz_relvh;

  if (ws_size >= need) {
    h16* gproj  = (h16*)((char*)d_ws + off_gproj);
    h16* woh    = (h16*)((char*)d_ws + off_woh);
    h16* relvh  = (h16*)((char*)d_ws + off_relvh);
    relv_pack<<<dim3(28), 64, 0, stream>>>(relv, relvh);
    proj_gemm<<<dim3(SEQ/64, NHEAD, 4), 256, 0, stream>>>(qkv, relk, gproj);
    wo_convert<<<dim3(HID*HID/4/256), 256, 0, stream>>>(Wo, woh);
    attn_fused<true><<<dim3(1024), 256, 0, stream>>>(qkv, relk, relv, gproj, relvh, xh);
    out_proj<true><<<dim3((4*SEQ)/64, HID/64), 256, 0, stream>>>(xh, Wo, woh, bo, out);
  } else {
    h16* relvh = (h16*)((char*)d_ws + sz_xh);   // fallback layout: xh | relvh
    relv_pack<<<dim3(28), 64, 0, stream>>>(relv, relvh);
    attn_fused<false><<<dim3(1024), 256, 0, stream>>>(qkv, relk, relv, nullptr, relvh, xh);
    out_proj<false><<<dim3((4*SEQ)/64, HID/64), 256, 0, stream>>>(xh, Wo, nullptr, bo, out);
  }
}

// Round 8
// 373.644 us; speedup vs baseline: 1.4362x; 1.4362x over previous
//
#include <hip/hip_runtime.h>
#include <hip/hip_fp16.h>
#include <type_traits>

// MultiHeadRelativeAttention (B=4, S=2048, H=8, dh=64, MAX_REL=96)
// K0a: proj = Q @ relk^T as f16 MFMA GEMM -> gproj
// K0b: Wo -> f16
// K0c: relv -> pre-packed MFMA B-frags (h16), zero-padded to 224 bins
// K1 : fused rel-pos flash attention, 3 blocks/CU (53248 B LDS exactly):
//      - K/V prefetched into regs one tile ahead, staged to XOR-swizzled LDS
//        (R5 mechanism, R7 showed sync global K loads cost +55us)
//      - XOR swizzle col^((row&7)<<3) on K/Vt/P: row strides are 32 dw = 0 mod 32,
//        unswizzled reads would be 16-way conflicts
//      - attnR bins in h16, plain RMW (race-free: rv injective per 16-aligned
//        k-block; rows wave-owned; clip bins in registers)
//      - pure-clip tile classification (~22/32 tiles skip gather/RMW entirely)
//      - w2 epilogue as 7x4 MFMAs vs pre-packed relv frags (needs stride >= 224)
// K2 : x @ Wo^T + bo (f16 MFMA)

#define SEQ   2048
#define NHEAD 8
#define DH    64
#define HID   512
#define ROWW  1536   // qkv row stride in floats (3*512)
#define QT    64
#define GPS   196    // gproj row stride (193 bins, padded)

#define C_L2E8 0.180336880111120f   // 0.125 * log2(e): softmax scale folded into exp2

typedef _Float16 h16;
typedef __attribute__((ext_vector_type(4))) float    f32x4;
typedef __attribute__((ext_vector_type(8))) _Float16 h16x8;
typedef __attribute__((ext_vector_type(4))) _Float16 h16x4;

static __device__ __forceinline__ h16x8 pack8(float4 a, float4 b) {
  h16x8 r;
  r[0]=(h16)a.x; r[1]=(h16)a.y; r[2]=(h16)a.z; r[3]=(h16)a.w;
  r[4]=(h16)b.x; r[5]=(h16)b.y; r[6]=(h16)b.z; r[7]=(h16)b.w;
  return r;
}

// LDS geometry (bank-exact):
//  attnRh stride 224 h16 = 112 dw = 16 mod 32 -> epilogue b128 reads uniform (8/bank).
//  K/Vt/P row stride 64 h16 = 32 dw = 0 mod 32 -> XOR swizzle col^((row&7)<<3)
//  applied on BOTH sides; b128 reads land 8 accesses/bank (minimum).
struct alignas(16) SmBase {
  h16 attnRh[64][224];   // 28672 B  per-q-row bin mass (cols 0/192 clip; 193-223 zero)
  h16 K[64][64];         //  8192 B  K tile [k][d^swz(k)]
  h16 Vt[64][64];        //  8192 B  V tile transposed [d][k^swz(d)]
  h16 P[4][16][64];      //  8192 B  per-wave P staging [q][k^swz(q)]
};                       // 53248 B -> 3 blocks/CU (159744 <= 163840)
struct alignas(16) SmFull {
  h16 attnRh[64][224];
  h16 K[64][64];
  h16 Vt[64][64];
  h16 P[4][16][64];
  h16 projh[64][194];    // fallback: proj in LDS -> 78080 B, 2 blocks/CU
};

// ---------------- K0a: proj = Q @ relk^T (MFMA) ----------------
__global__ __launch_bounds__(256)
void proj_gemm(const float* __restrict__ qkv, const float* __restrict__ relk,
               h16* __restrict__ gproj)
{
  const int qt = blockIdx.x, h = blockIdx.y, b = blockIdx.z;
  const int tid = (int)threadIdx.x;
  const int w = tid >> 6, l = tid & 63, l15 = l & 15, l4 = l >> 4;
  const int q0 = qt * 64;

  const float* qr = qkv + ((size_t)(b*SEQ) + q0 + w*16 + l15) * ROWW + h*DH + l4*8;
  h16x8 aq0 = pack8(*(const float4*)(qr),      *(const float4*)(qr + 4));
  h16x8 aq1 = pack8(*(const float4*)(qr + 32), *(const float4*)(qr + 36));

  h16* orow = gproj + ((size_t)(b*NHEAD + h)*SEQ + q0 + w*16) * GPS;

#pragma unroll
  for (int nt = 0; nt < 13; ++nt) {
    const int n0 = nt * 16;
    const int rc = (n0 + l15 > 192) ? 192 : n0 + l15;   // clamp tail tile
    const float* rkp = relk + rc*DH + l4*8;
    h16x8 b0 = pack8(*(const float4*)(rkp),      *(const float4*)(rkp + 4));
    h16x8 b1 = pack8(*(const float4*)(rkp + 32), *(const float4*)(rkp + 36));
    f32x4 z = {};
    z = __builtin_amdgcn_mfma_f32_16x16x32_f16(aq0, b0, z, 0, 0, 0);
    z = __builtin_amdgcn_mfma_f32_16x16x32_f16(aq1, b1, z, 0, 0, 0);
    if (n0 + l15 < GPS) {
#pragma unroll
      for (int j = 0; j < 4; ++j)
        orow[(size_t)(l4*4 + j)*GPS + n0 + l15] = (h16)z[j];
    }
  }
}

// ---------------- K0b: Wo -> f16 ----------------
__global__ __launch_bounds__(256)
void wo_convert(const float* __restrict__ Wo, h16* __restrict__ Woh)
{
  const size_t i = (size_t)blockIdx.x * 256 + threadIdx.x;
  float4 v = *(const float4*)(Wo + i*4);
  h16x4 o; o[0]=(h16)v.x; o[1]=(h16)v.y; o[2]=(h16)v.z; o[3]=(h16)v.w;
  *(h16x4*)(Woh + i*4) = o;
}

// ---------------- K0c: relv -> pre-packed B-frags ----------------
__global__ void relv_pack(const float* __restrict__ relv, h16* __restrict__ relvh)
{
  const int bi = (int)blockIdx.x;
  const int l = (int)threadIdx.x, l15 = l & 15, l4 = l >> 4;
  const int kblk = bi >> 2, vc = bi & 3;
  h16x8 o;
#pragma unroll
  for (int e = 0; e < 8; ++e) {
    const int k = kblk*32 + l4*8 + e;
    o[e] = (k < 193) ? (h16)relv[k*DH + vc*16 + l15] : (h16)0.f;
  }
  *(h16x8*)(relvh + ((size_t)bi*64 + l)*8) = o;
}

// ---------------- K1: fused relative attention ----------------
template<bool GP>
__global__ __launch_bounds__(256, 3)
void attn_fused(const float* __restrict__ qkv,
                const float* __restrict__ relk,
                const float* __restrict__ relv,
                const h16* __restrict__ gproj,
                const h16* __restrict__ relvh,
                h16* __restrict__ xout)
{
  using SM = typename std::conditional<GP, SmBase, SmFull>::type;
  __shared__ SM sm;

  // XCD-chunked swizzle: 1024 wgs, 8 XCDs, 128 contiguous work-ids per XCD.
  const int wg = (int)blockIdx.x;
  const int id = (wg & 7) * 128 + (wg >> 3);
  const int qt = id & 31, h = (id >> 5) & 7, b = id >> 8;

  const int tid = (int)threadIdx.x;
  const int w = tid >> 6, l = tid & 63, l15 = l & 15, l4 = l >> 4;
  const int q0 = qt * QT;
  const int dl = l, kq = w;   // V-staging roles

  const float* qbase = qkv + ((size_t)(b*SEQ) + q0) * ROWW + h*DH;
  const float* kbase = qkv + (size_t)(b*SEQ) * ROWW + HID   + h*DH;
  const float* vbase = qkv + (size_t)(b*SEQ) * ROWW + 2*HID + h*DH;
  const h16* gprow = gproj + ((size_t)(b*NHEAD + h)*SEQ + q0 + w*16) * GPS;

  // zero attnRh (int4 stores)
  {
    int4* az = (int4*)&sm.attnRh[0][0];
#pragma unroll 2
    for (int i = tid; i < (int)(sizeof(sm.attnRh)/16); i += 256)
      az[i] = make_int4(0,0,0,0);
  }

  if constexpr (!GP) {
    const int prow = tid >> 2, psub = tid & 3;
    const float* qrow = qbase + (size_t)prow * ROWW;
    float4 qv[16];
#pragma unroll
    for (int c = 0; c < 16; ++c) qv[c] = *(const float4*)(qrow + c*4);
    for (int r = psub; r < 193; r += 4) {
      const float4* rk = (const float4*)(relk + r*DH);
      float acc1 = 0.f;
#pragma unroll
      for (int c = 0; c < 16; ++c) {
        float4 tt = rk[c];
        acc1 += qv[c].x*tt.x + qv[c].y*tt.y + qv[c].z*tt.z + qv[c].w*tt.w;
      }
      sm.projh[prow][r] = (h16)acc1;
    }
  }

  // Q A-fragments: A[m=l15][k=l4*8+e]
  h16x8 aq0, aq1;
  {
    const float* qr = qbase + (size_t)(w*16 + l15) * ROWW + l4*8;
    aq0 = pack8(*(const float4*)(qr),      *(const float4*)(qr + 4));
    aq1 = pack8(*(const float4*)(qr + 32), *(const float4*)(qr + 36));
  }

  int rvq[4];
#pragma unroll
  for (int j = 0; j < 4; ++j) {
    int qg = q0 + w*16 + l4*4 + j;
    rvq[j] = (qg <= 1024) ? qg : (2048 - qg);
  }

  // wave-level rvq range (rv peaks at 1024; min at endpoints)
  const int qa = q0 + w*16, qb = qa + 15;
  const int rqa = (qa <= 1024) ? qa : 2048 - qa;
  const int rqb = (qb <= 1024) ? qb : 2048 - qb;
  const int rvqmin = rqa < rqb ? rqa : rqb;
  const int rvqmax = (qa <= 1024 && 1024 <= qb) ? 1024 : (rqa > rqb ? rqa : rqb);

  // tile class: 0 = all clip to bin 0, 2 = all clip to bin 192, 1 = mixed
  auto classify = [&](int KT) -> int {
    const int ka = KT*64, kb = ka + 63;
    const int ra = (ka <= 1024) ? ka : 2048 - ka;
    const int rb = (kb <= 1024) ? kb : 2048 - kb;
    const int rmin = ra < rb ? ra : rb;
    const int rmax = (ka <= 1024 && 1024 <= kb) ? 1024 : (ra > rb ? ra : rb);
    if (rmax <= rvqmin - 96) return 0;
    if (rmin >= rvqmax + 96) return 2;
    return 1;
  };

  f32x4 acc[4] = {};
  float lsum[4] = {0.f,0.f,0.f,0.f};
  float c0[4]   = {0.f,0.f,0.f,0.f};
  float c192[4] = {0.f,0.f,0.f,0.f};

  float4 kreg[4];      // cooperative K staging (1024 float4 over 256 thr x 4)
  float  vreg[4][4];   // V column staging

  auto kvIssue = [&](int KT) {
    const int kk = KT * 64;
#pragma unroll
    for (int m = 0; m < 4; ++m) {
      const int idx4 = tid + 256*m;
      kreg[m] = *(const float4*)(kbase + (size_t)(kk + (idx4>>4))*ROWW + (idx4&15)*4);
    }
#pragma unroll
    for (int m = 0; m < 4; ++m)
#pragma unroll
      for (int e = 0; e < 4; ++e)
        vreg[m][e] = vbase[(size_t)(kk + m*16 + kq*4 + e)*ROWW + dl];
  };

  auto kvWrite = [&]() {
#pragma unroll
    for (int m = 0; m < 4; ++m) {
      const int idx4 = tid + 256*m;
      const int kr = idx4 >> 4, c4 = idx4 & 15;
      h16x4 t; t[0]=(h16)kreg[m].x; t[1]=(h16)kreg[m].y; t[2]=(h16)kreg[m].z; t[3]=(h16)kreg[m].w;
      *(h16x4*)(&sm.K[kr][(c4*4) ^ ((kr & 7) << 3)]) = t;
    }
#pragma unroll
    for (int m = 0; m < 4; ++m) {
      h16x4 u; u[0]=(h16)vreg[m][0]; u[1]=(h16)vreg[m][1]; u[2]=(h16)vreg[m][2]; u[3]=(h16)vreg[m][3];
      *(h16x4*)(&sm.Vt[dl][(m*16 + kq*4) ^ ((dl & 7) << 3)]) = u;
    }
  };

  // ---- prologue ----
  int cls = classify(0);
  kvIssue(0);
  kvWrite();
  __syncthreads();   // covers attnRh zeroing, projh (!GP), K/Vt(0)

  float proj0f[4], proj192f[4], C0e[4], C192e[4];
  if constexpr (GP) {
#pragma unroll
    for (int j = 0; j < 4; ++j) {
      proj0f[j]   = (float)gprow[(size_t)(l4*4 + j)*GPS + 0];
      proj192f[j] = (float)gprow[(size_t)(l4*4 + j)*GPS + 192];
    }
  } else {
#pragma unroll
    for (int j = 0; j < 4; ++j) {
      proj0f[j]   = (float)sm.projh[w*16 + l4*4 + j][0];
      proj192f[j] = (float)sm.projh[w*16 + l4*4 + j][192];
    }
  }
#pragma unroll
  for (int j = 0; j < 4; ++j) {
    C0e[j]   = exp2f(proj0f[j]   * C_L2E8);
    C192e[j] = exp2f(proj192f[j] * C_L2E8);
  }

  const int kswz = (l15 & 7) << 3;   // read-side XOR for K/Vt/P (row ends in l15)

  for (int kt = 0; kt < 32; ++kt) {
    const int kk = kt * 64;

    // ---- QK^T from swizzled K LDS ----
    f32x4 sc[4];
#pragma unroll
    for (int ct = 0; ct < 4; ++ct) {
      h16x8 kb0 = *(const h16x8*)(&sm.K[ct*16 + l15][(l4*8) ^ kswz]);
      h16x8 kb1 = *(const h16x8*)(&sm.K[ct*16 + l15][(32 + l4*8) ^ kswz]);
      f32x4 z = {};
      z = __builtin_amdgcn_mfma_f32_16x16x32_f16(aq0, kb0, z, 0, 0, 0);
      z = __builtin_amdgcn_mfma_f32_16x16x32_f16(aq1, kb1, z, 0, 0, 0);
      sc[ct] = z;
    }

    if (kt < 31) kvIssue(kt + 1);   // prefetch next K/V tile into regs

    // ---- middle: rel-pos add, exp, bin mass, P staging ----
    if (cls == 1) {
#pragma unroll
      for (int ct = 0; ct < 4; ++ct) {
        const int kg = kk + ct*16 + l15;
        const int rvk = (kg <= 1024) ? kg : (2048 - kg);
#pragma unroll
        for (int j = 0; j < 4; ++j) {
          const int rowL = w*16 + l4*4 + j;
          int dd = rvk - rvq[j];
          dd = dd < -96 ? -96 : (dd > 96 ? 96 : dd);
          const int bin = dd + 96;
          float pj;
          if constexpr (GP) {
            pj = (bin == 0) ? proj0f[j]
               : (bin == 192) ? proj192f[j]
               : (float)gprow[(size_t)(l4*4 + j)*GPS + bin];
          } else {
            pj = (float)sm.projh[rowL][bin];
          }
          const float p = exp2f((sc[ct][j] + pj) * C_L2E8);
          lsum[j] += p;
          if (bin == 0)        c0[j]   += p;
          else if (bin == 192) c192[j] += p;
          else {
            // race-free RMW: distinct (row,bin) per lane within each instruction
            h16 old = sm.attnRh[rowL][bin];
            sm.attnRh[rowL][bin] = old + (h16)p;
          }
          sm.P[w][l4*4 + j][(ct*16 + l15) ^ (((l4*4 + j) & 7) << 3)] = (h16)p;
        }
      }
    } else if (cls == 0) {
#pragma unroll
      for (int ct = 0; ct < 4; ++ct) {
#pragma unroll
        for (int j = 0; j < 4; ++j) {
          const float p = exp2f(sc[ct][j] * C_L2E8) * C0e[j];
          lsum[j] += p;
          c0[j]   += p;
          sm.P[w][l4*4 + j][(ct*16 + l15) ^ (((l4*4 + j) & 7) << 3)] = (h16)p;
        }
      }
    } else {
#pragma unroll
      for (int ct = 0; ct < 4; ++ct) {
#pragma unroll
        for (int j = 0; j < 4; ++j) {
          const float p = exp2f(sc[ct][j] * C_L2E8) * C192e[j];
          lsum[j] += p;
          c192[j] += p;
          sm.P[w][l4*4 + j][(ct*16 + l15) ^ (((l4*4 + j) & 7) << 3)] = (h16)p;
        }
      }
    }

    // ---- PV: acc += P V (swizzled P and Vt reads) ----
    {
      h16x8 pa0 = *(const h16x8*)(&sm.P[w][l15][(l4*8) ^ kswz]);
      h16x8 pa1 = *(const h16x8*)(&sm.P[w][l15][(32 + l4*8) ^ kswz]);
#pragma unroll
      for (int vc = 0; vc < 4; ++vc) {
        const int d = vc*16 + l15;
        h16x8 vb0 = *(const h16x8*)(&sm.Vt[d][(l4*8) ^ kswz]);
        h16x8 vb1 = *(const h16x8*)(&sm.Vt[d][(32 + l4*8) ^ kswz]);
        acc[vc] = __builtin_amdgcn_mfma_f32_16x16x32_f16(pa0, vb0, acc[vc], 0, 0, 0);
        acc[vc] = __builtin_amdgcn_mfma_f32_16x16x32_f16(pa1, vb1, acc[vc], 0, 0, 0);
      }
    }

    __syncthreads();                              // all waves done with K/Vt(kt)
    if (kt < 31) { kvWrite(); cls = classify(kt + 1); }
    __syncthreads();                              // K/Vt(kt+1) visible
  }

  // ---- fold clip masses + lsum over the 16-lane row group ----
#pragma unroll
  for (int j = 0; j < 4; ++j) {
    for (int mask = 1; mask < 16; mask <<= 1) {
      c0[j]   += __shfl_xor(c0[j],   mask);
      c192[j] += __shfl_xor(c192[j], mask);
      lsum[j] += __shfl_xor(lsum[j], mask);
    }
  }
  if (l15 == 0) {
#pragma unroll
    for (int j = 0; j < 4; ++j) {
      sm.attnRh[w*16 + l4*4 + j][0]   = (h16)c0[j];
      sm.attnRh[w*16 + l4*4 + j][192] = (h16)c192[j];
    }
  }
  // no barrier: attnRh rows are wave-local; LDS ops are in-order per wave

  // ---- w2 epilogue: acc += attnRh @ relv (7 k-blocks x 4 col-tiles MFMA) ----
#pragma unroll
  for (int kb6 = 0; kb6 < 7; ++kb6) {
    h16x8 pa = *(const h16x8*)(&sm.attnRh[w*16 + l15][kb6*32 + l4*8]);
#pragma unroll
    for (int vc = 0; vc < 4; ++vc) {
      h16x8 bf = *(const h16x8*)(relvh + ((size_t)((kb6*4 + vc)*64 + l))*8);
      acc[vc] = __builtin_amdgcn_mfma_f32_16x16x32_f16(pa, bf, acc[vc], 0, 0, 0);
    }
  }

  // ---- normalize + store x (f16) ----
  float inv[4];
#pragma unroll
  for (int j = 0; j < 4; ++j) inv[j] = 1.f / lsum[j];
#pragma unroll
  for (int vc = 0; vc < 4; ++vc) {
#pragma unroll
    for (int j = 0; j < 4; ++j) {
      const int row16 = l4*4 + j;
      const int col   = vc*16 + l15;
      xout[((size_t)(b*SEQ) + q0 + w*16 + row16) * HID + h*DH + col] =
          (h16)(acc[vc][j] * inv[j]);
    }
  }
}

// ---------------- K2: out = x @ Wo^T + bo ----------------
template<bool WH>
__global__ __launch_bounds__(256)
void out_proj(const h16* __restrict__ xh,
              const float* __restrict__ Wo,
              const h16* __restrict__ Woh,
              const float* __restrict__ bo,
              float* __restrict__ out)
{
  const int tid = (int)threadIdx.x;
  const int w = tid >> 6, l = tid & 63, l15 = l & 15, l4 = l >> 4;
  const int m0 = blockIdx.x * 64 + w * 16;
  const int n0 = blockIdx.y * 64;
  f32x4 acc[4] = {};
  const h16* arow = xh + (size_t)(m0 + l15) * HID + l4*8;
#pragma unroll
  for (int ks = 0; ks < 16; ++ks) {
    h16x8 a = *(const h16x8*)(arow + ks*32);
#pragma unroll
    for (int ct = 0; ct < 4; ++ct) {
      h16x8 bfrag;
      if constexpr (WH) {
        bfrag = *(const h16x8*)(Woh + (size_t)(n0 + ct*16 + l15) * HID + ks*32 + l4*8);
      } else {
        const float* wrow = Wo + (size_t)(n0 + ct*16 + l15) * HID + ks*32 + l4*8;
        bfrag = pack8(*(const float4*)wrow, *(const float4*)(wrow + 4));
      }
      acc[ct] = __builtin_amdgcn_mfma_f32_16x16x32_f16(a, bfrag, acc[ct], 0, 0, 0);
    }
  }
#pragma unroll
  for (int ct = 0; ct < 4; ++ct) {
    const int col = n0 + ct*16 + l15;
    const float bv = bo[col];
#pragma unroll
    for (int j = 0; j < 4; ++j)
      out[(size_t)(m0 + l4*4 + j) * HID + col] = acc[ct][j] + bv;
  }
}

extern "C" void kernel_launch(void* const* d_in, const int* in_sizes, int n_in,
                              void* d_out, int out_size, void* d_ws, size_t ws_size,
                              hipStream_t stream)
{
  const float* qkv  = (const float*)d_in[0];
  const float* relk = (const float*)d_in[1];
  const float* relv = (const float*)d_in[2];
  const float* Wo   = (const float*)d_in[3];
  const float* bo   = (const float*)d_in[4];
  float* out = (float*)d_out;

  const size_t sz_xh    = (size_t)4*SEQ*HID*2;            //  8.39 MB
  const size_t sz_gproj = (size_t)4*NHEAD*SEQ*GPS*2;      // 25.69 MB
  const size_t sz_woh   = (size_t)HID*HID*2;              //  0.52 MB
  const size_t sz_relvh = (size_t)28*64*8*2;              // 28672 B

  h16* xh = (h16*)d_ws;

  const size_t off_gproj = sz_xh;
  const size_t off_woh   = off_gproj + sz_gproj;
  const size_t off_relvh = off_woh + sz_woh;
  const size_t need      = off_relvh + sz_relvh;

  if (ws_size >= need) {
    h16* gproj  = (h16*)((char*)d_ws + off_gproj);
    h16* woh    = (h16*)((char*)d_ws + off_woh);
    h16* relvh  = (h16*)((char*)d_ws + off_relvh);
    relv_pack<<<dim3(28), 64, 0, stream>>>(relv, relvh);
    proj_gemm<<<dim3(SEQ/64, NHEAD, 4), 256, 0, stream>>>(qkv, relk, gproj);
    wo_convert<<<dim3(HID*HID/4/256), 256, 0, stream>>>(Wo, woh);
    attn_fused<true><<<dim3(1024), 256, 0, stream>>>(qkv, relk, relv, gproj, relvh, xh);
    out_proj<true><<<dim3((4*SEQ)/64, HID/64), 256, 0, stream>>>(xh, Wo, woh, bo, out);
  } else {
    h16* relvh = (h16*)((char*)d_ws + sz_xh);   // fallback layout: xh | relvh
    relv_pack<<<dim3(28), 64, 0, stream>>>(relv, relvh);
    attn_fused<false><<<dim3(1024), 256, 0, stream>>>(qkv, relk, relv, nullptr, relvh, xh);
    out_proj<false><<<dim3((4*SEQ)/64, HID/64), 256, 0, stream>>>(xh, Wo, nullptr, bo, out);
  }
}

// Round 9
// 350.966 us; speedup vs baseline: 1.5290x; 1.0646x over previous
//
#include <hip/hip_runtime.h>
#include <hip/hip_fp16.h>
#include <type_traits>

// MultiHeadRelativeAttention (B=4, S=2048, H=8, dh=64, MAX_REL=96)
// K0a: proj = Q @ relk^T as f16 MFMA GEMM -> gproj
// K0b: Wo -> f16
// K0c: relv -> pre-packed MFMA B-frags (h16), zero-padded to 224 bins
// K1 : fused rel-pos flash attention, single barrier per k-tile:
//      - K/V double-buffered in LDS (69.6 KB; occupancy counter proved extra
//        LDS is free: pinned ~22% across 50-117 KB configs)
//      - K/V prefetched into regs one tile ahead (R8-proven mechanism)
//      - XOR swizzle col^((row&7)<<3) on K/Vt/P (R8: conflicts 7.5e6->3.9e6)
//      - gproj gathers for mixed tiles prefetched one tile ahead (R5 mechanism)
//      - attnR bins h16 plain RMW (race-free), clip bins in registers
//      - pure-clip tile classification; clip const folded into exp2 arg
//      - w2 epilogue as 7x4 MFMAs vs pre-packed relv frags
// K2 : x @ Wo^T + bo (f16 MFMA)

#define SEQ   2048
#define NHEAD 8
#define DH    64
#define HID   512
#define ROWW  1536   // qkv row stride in floats (3*512)
#define QT    64
#define GPS   196    // gproj row stride (193 bins, padded)

#define C_L2E8 0.180336880111120f   // 0.125 * log2(e): softmax scale folded into exp2

typedef _Float16 h16;
typedef __attribute__((ext_vector_type(4))) float    f32x4;
typedef __attribute__((ext_vector_type(8))) _Float16 h16x8;
typedef __attribute__((ext_vector_type(4))) _Float16 h16x4;

static __device__ __forceinline__ h16x8 pack8(float4 a, float4 b) {
  h16x8 r;
  r[0]=(h16)a.x; r[1]=(h16)a.y; r[2]=(h16)a.z; r[3]=(h16)a.w;
  r[4]=(h16)b.x; r[5]=(h16)b.y; r[6]=(h16)b.z; r[7]=(h16)b.w;
  return r;
}

// LDS geometry: attnRh stride 224 h16; K/Vt/P stride 64 h16 (0 mod 32 dw) with
// XOR swizzle col^((row&7)<<3) on both write and read sides.
struct alignas(16) SmBase {
  h16 attnRh[64][224];    // 28672 B  per-q-row bin mass (cols 0/192 clip; 193-223 zero)
  h16 K[2][64][64];       // 16384 B  K tile dbuf [k][d^swz(k)]
  h16 Vt[2][64][64];      // 16384 B  V tile transposed dbuf [d][k^swz(d)]
  h16 P[4][16][64];       //  8192 B  per-wave P staging [q][k^swz(q)]
};                        // 69632 B -> 2 blocks/CU
struct alignas(16) SmFull {
  h16 attnRh[64][224];
  h16 K[2][64][64];
  h16 Vt[2][64][64];
  h16 P[4][16][64];
  h16 projh[64][194];     // fallback: proj in LDS -> 94464 B, 1 block/CU
};

// ---------------- K0a: proj = Q @ relk^T (MFMA) ----------------
__global__ __launch_bounds__(256)
void proj_gemm(const float* __restrict__ qkv, const float* __restrict__ relk,
               h16* __restrict__ gproj)
{
  const int qt = blockIdx.x, h = blockIdx.y, b = blockIdx.z;
  const int tid = (int)threadIdx.x;
  const int w = tid >> 6, l = tid & 63, l15 = l & 15, l4 = l >> 4;
  const int q0 = qt * 64;

  const float* qr = qkv + ((size_t)(b*SEQ) + q0 + w*16 + l15) * ROWW + h*DH + l4*8;
  h16x8 aq0 = pack8(*(const float4*)(qr),      *(const float4*)(qr + 4));
  h16x8 aq1 = pack8(*(const float4*)(qr + 32), *(const float4*)(qr + 36));

  h16* orow = gproj + ((size_t)(b*NHEAD + h)*SEQ + q0 + w*16) * GPS;

#pragma unroll
  for (int nt = 0; nt < 13; ++nt) {
    const int n0 = nt * 16;
    const int rc = (n0 + l15 > 192) ? 192 : n0 + l15;   // clamp tail tile
    const float* rkp = relk + rc*DH + l4*8;
    h16x8 b0 = pack8(*(const float4*)(rkp),      *(const float4*)(rkp + 4));
    h16x8 b1 = pack8(*(const float4*)(rkp + 32), *(const float4*)(rkp + 36));
    f32x4 z = {};
    z = __builtin_amdgcn_mfma_f32_16x16x32_f16(aq0, b0, z, 0, 0, 0);
    z = __builtin_amdgcn_mfma_f32_16x16x32_f16(aq1, b1, z, 0, 0, 0);
    if (n0 + l15 < GPS) {
#pragma unroll
      for (int j = 0; j < 4; ++j)
        orow[(size_t)(l4*4 + j)*GPS + n0 + l15] = (h16)z[j];
    }
  }
}

// ---------------- K0b: Wo -> f16 ----------------
__global__ __launch_bounds__(256)
void wo_convert(const float* __restrict__ Wo, h16* __restrict__ Woh)
{
  const size_t i = (size_t)blockIdx.x * 256 + threadIdx.x;
  float4 v = *(const float4*)(Wo + i*4);
  h16x4 o; o[0]=(h16)v.x; o[1]=(h16)v.y; o[2]=(h16)v.z; o[3]=(h16)v.w;
  *(h16x4*)(Woh + i*4) = o;
}

// ---------------- K0c: relv -> pre-packed B-frags ----------------
__global__ void relv_pack(const float* __restrict__ relv, h16* __restrict__ relvh)
{
  const int bi = (int)blockIdx.x;
  const int l = (int)threadIdx.x, l15 = l & 15, l4 = l >> 4;
  const int kblk = bi >> 2, vc = bi & 3;
  h16x8 o;
#pragma unroll
  for (int e = 0; e < 8; ++e) {
    const int k = kblk*32 + l4*8 + e;
    o[e] = (k < 193) ? (h16)relv[k*DH + vc*16 + l15] : (h16)0.f;
  }
  *(h16x8*)(relvh + ((size_t)bi*64 + l)*8) = o;
}

// ---------------- K1: fused relative attention ----------------
template<bool GP>
__global__ __launch_bounds__(256, 2)
void attn_fused(const float* __restrict__ qkv,
                const float* __restrict__ relk,
                const float* __restrict__ relv,
                const h16* __restrict__ gproj,
                const h16* __restrict__ relvh,
                h16* __restrict__ xout)
{
  using SM = typename std::conditional<GP, SmBase, SmFull>::type;
  __shared__ SM sm;

  // XCD-chunked swizzle: 1024 wgs, 8 XCDs, 128 contiguous work-ids per XCD.
  const int wg = (int)blockIdx.x;
  const int id = (wg & 7) * 128 + (wg >> 3);
  const int qt = id & 31, h = (id >> 5) & 7, b = id >> 8;

  const int tid = (int)threadIdx.x;
  const int w = tid >> 6, l = tid & 63, l15 = l & 15, l4 = l >> 4;
  const int q0 = qt * QT;
  const int dl = l, kq = w;   // V-staging roles

  const float* qbase = qkv + ((size_t)(b*SEQ) + q0) * ROWW + h*DH;
  const float* kbase = qkv + (size_t)(b*SEQ) * ROWW + HID   + h*DH;
  const float* vbase = qkv + (size_t)(b*SEQ) * ROWW + 2*HID + h*DH;
  const h16* gprow = gproj + ((size_t)(b*NHEAD + h)*SEQ + q0 + w*16) * GPS;

  // zero attnRh (int4 stores)
  {
    int4* az = (int4*)&sm.attnRh[0][0];
#pragma unroll 2
    for (int i = tid; i < (int)(sizeof(sm.attnRh)/16); i += 256)
      az[i] = make_int4(0,0,0,0);
  }

  if constexpr (!GP) {
    const int prow = tid >> 2, psub = tid & 3;
    const float* qrow = qbase + (size_t)prow * ROWW;
    float4 qv[16];
#pragma unroll
    for (int c = 0; c < 16; ++c) qv[c] = *(const float4*)(qrow + c*4);
    for (int r = psub; r < 193; r += 4) {
      const float4* rk = (const float4*)(relk + r*DH);
      float acc1 = 0.f;
#pragma unroll
      for (int c = 0; c < 16; ++c) {
        float4 tt = rk[c];
        acc1 += qv[c].x*tt.x + qv[c].y*tt.y + qv[c].z*tt.z + qv[c].w*tt.w;
      }
      sm.projh[prow][r] = (h16)acc1;
    }
  }

  // Q A-fragments: A[m=l15][k=l4*8+e]
  h16x8 aq0, aq1;
  {
    const float* qr = qbase + (size_t)(w*16 + l15) * ROWW + l4*8;
    aq0 = pack8(*(const float4*)(qr),      *(const float4*)(qr + 4));
    aq1 = pack8(*(const float4*)(qr + 32), *(const float4*)(qr + 36));
  }

  int rvq[4];
#pragma unroll
  for (int j = 0; j < 4; ++j) {
    int qg = q0 + w*16 + l4*4 + j;
    rvq[j] = (qg <= 1024) ? qg : (2048 - qg);
  }

  // wave-level rvq range (rv peaks at 1024; min at endpoints)
  const int qa = q0 + w*16, qb = qa + 15;
  const int rqa = (qa <= 1024) ? qa : 2048 - qa;
  const int rqb = (qb <= 1024) ? qb : 2048 - qb;
  const int rvqmin = rqa < rqb ? rqa : rqb;
  const int rvqmax = (qa <= 1024 && 1024 <= qb) ? 1024 : (rqa > rqb ? rqa : rqb);

  // tile class: 0 = all clip to bin 0, 2 = all clip to bin 192, 1 = mixed
  auto classify = [&](int KT) -> int {
    const int ka = KT*64, kb = ka + 63;
    const int ra = (ka <= 1024) ? ka : 2048 - ka;
    const int rb = (kb <= 1024) ? kb : 2048 - kb;
    const int rmin = ra < rb ? ra : rb;
    const int rmax = (ka <= 1024 && 1024 <= kb) ? 1024 : (ra > rb ? ra : rb);
    if (rmax <= rvqmin - 96) return 0;
    if (rmin >= rvqmax + 96) return 2;
    return 1;
  };

  f32x4 acc[4] = {};
  float lsum[4] = {0.f,0.f,0.f,0.f};   // interior-bin mass only (clips added at end)
  float c0[4]   = {0.f,0.f,0.f,0.f};
  float c192[4] = {0.f,0.f,0.f,0.f};

  float4 kreg[4];      // cooperative K staging (1024 float4 over 256 thr x 4)
  float  vreg[4][4];   // V column staging
  int    bins[4][4];   // prefetched bin ids (mixed tiles)
  float  pvf[4][4];    // prefetched proj values (mixed tiles)

  auto kvIssue = [&](int KT) {
    const int kk = KT * 64;
#pragma unroll
    for (int m = 0; m < 4; ++m) {
      const int idx4 = tid + 256*m;
      kreg[m] = *(const float4*)(kbase + (size_t)(kk + (idx4>>4))*ROWW + (idx4&15)*4);
    }
#pragma unroll
    for (int m = 0; m < 4; ++m)
#pragma unroll
      for (int e = 0; e < 4; ++e)
        vreg[m][e] = vbase[(size_t)(kk + m*16 + kq*4 + e)*ROWW + dl];
  };

  auto kvWrite = [&](int buf) {
#pragma unroll
    for (int m = 0; m < 4; ++m) {
      const int idx4 = tid + 256*m;
      const int kr = idx4 >> 4, c4 = idx4 & 15;
      h16x4 t; t[0]=(h16)kreg[m].x; t[1]=(h16)kreg[m].y; t[2]=(h16)kreg[m].z; t[3]=(h16)kreg[m].w;
      *(h16x4*)(&sm.K[buf][kr][(c4*4) ^ ((kr & 7) << 3)]) = t;
    }
#pragma unroll
    for (int m = 0; m < 4; ++m) {
      h16x4 u; u[0]=(h16)vreg[m][0]; u[1]=(h16)vreg[m][1]; u[2]=(h16)vreg[m][2]; u[3]=(h16)vreg[m][3];
      *(h16x4*)(&sm.Vt[buf][dl][(m*16 + kq*4) ^ ((dl & 7) << 3)]) = u;
    }
  };

  float proj0f[4], proj192f[4];

  // gather prefetch for a mixed tile: bins + proj value (clips -> register consts)
  auto gatherIssue = [&](int KT) {
#pragma unroll
    for (int ct = 0; ct < 4; ++ct) {
      const int kg = KT*64 + ct*16 + l15;
      const int rvk = (kg <= 1024) ? kg : (2048 - kg);
#pragma unroll
      for (int j = 0; j < 4; ++j) {
        int dd = rvk - rvq[j];
        dd = dd < -96 ? -96 : (dd > 96 ? 96 : dd);
        const int bin = dd + 96;
        bins[ct][j] = bin;
        if constexpr (GP) {
          if (bin > 0 && bin < 192)
            pvf[ct][j] = (float)gprow[(size_t)(l4*4 + j)*GPS + bin];
          else
            pvf[ct][j] = (bin == 0) ? proj0f[j] : proj192f[j];
        }
      }
    }
  };

  // ---- prologue ----
  int cls = classify(0);
  kvIssue(0);
  kvWrite(0);          // K/V(0) -> buf 0
  kvIssue(1);          // K/V(1) in flight
  __syncthreads();     // covers attnRh zeroing, projh (!GP), K/Vt buf0

  if constexpr (GP) {
#pragma unroll
    for (int j = 0; j < 4; ++j) {
      proj0f[j]   = (float)gprow[(size_t)(l4*4 + j)*GPS + 0];
      proj192f[j] = (float)gprow[(size_t)(l4*4 + j)*GPS + 192];
    }
  } else {
#pragma unroll
    for (int j = 0; j < 4; ++j) {
      proj0f[j]   = (float)sm.projh[w*16 + l4*4 + j][0];
      proj192f[j] = (float)sm.projh[w*16 + l4*4 + j][192];
    }
  }
  if (cls == 1) gatherIssue(0);

  const int kswz = (l15 & 7) << 3;   // read-side XOR for K/Vt/P (row ends in l15)

  for (int kt = 0; kt < 32; ++kt) {
    const int cur = kt & 1;

    // ---- QK^T from swizzled K LDS (buf cur) ----
    f32x4 sc[4];
#pragma unroll
    for (int ct = 0; ct < 4; ++ct) {
      h16x8 kb0 = *(const h16x8*)(&sm.K[cur][ct*16 + l15][(l4*8) ^ kswz]);
      h16x8 kb1 = *(const h16x8*)(&sm.K[cur][ct*16 + l15][(32 + l4*8) ^ kswz]);
      f32x4 z = {};
      z = __builtin_amdgcn_mfma_f32_16x16x32_f16(aq0, kb0, z, 0, 0, 0);
      z = __builtin_amdgcn_mfma_f32_16x16x32_f16(aq1, kb1, z, 0, 0, 0);
      sc[ct] = z;
    }

    // ---- stage K/V(kt+1) into the other buffer; issue loads for kt+2 ----
    // Safe: buf cur^1 was last read at tile kt-1, protected by end-of-(kt-1) barrier.
    if (kt < 31) kvWrite(cur ^ 1);
    if (kt < 30) kvIssue(kt + 2);

    // ---- middle: rel-pos add, exp2, bin mass, P staging ----
    if (cls == 1) {
#pragma unroll
      for (int ct = 0; ct < 4; ++ct) {
#pragma unroll
        for (int j = 0; j < 4; ++j) {
          const int rowL = w*16 + l4*4 + j;
          const int bin = bins[ct][j];
          float pj;
          if constexpr (GP) pj = pvf[ct][j];
          else {
            pj = (float)sm.projh[rowL][bin];
          }
          const float p = exp2f((sc[ct][j] + pj) * C_L2E8);
          if (bin == 0)        c0[j]   += p;
          else if (bin == 192) c192[j] += p;
          else {
            lsum[j] += p;
            // race-free RMW: distinct (row,bin) per lane within each instruction
            h16 old = sm.attnRh[rowL][bin];
            sm.attnRh[rowL][bin] = old + (h16)p;
          }
          sm.P[w][l4*4 + j][(ct*16 + l15) ^ (((l4*4 + j) & 7) << 3)] = (h16)p;
        }
      }
    } else if (cls == 0) {
#pragma unroll
      for (int ct = 0; ct < 4; ++ct) {
#pragma unroll
        for (int j = 0; j < 4; ++j) {
          const float p = exp2f((sc[ct][j] + proj0f[j]) * C_L2E8);
          c0[j] += p;
          sm.P[w][l4*4 + j][(ct*16 + l15) ^ (((l4*4 + j) & 7) << 3)] = (h16)p;
        }
      }
    } else {
#pragma unroll
      for (int ct = 0; ct < 4; ++ct) {
#pragma unroll
        for (int j = 0; j < 4; ++j) {
          const float p = exp2f((sc[ct][j] + proj192f[j]) * C_L2E8);
          c192[j] += p;
          sm.P[w][l4*4 + j][(ct*16 + l15) ^ (((l4*4 + j) & 7) << 3)] = (h16)p;
        }
      }
    }

    // ---- prefetch gathers for next tile (after pvf/bins consumed) ----
    const int clsN = (kt < 31) ? classify(kt + 1) : 0;
    if (kt < 31 && clsN == 1) gatherIssue(kt + 1);

    // ---- PV: acc += P V (swizzled P and Vt reads, buf cur) ----
    {
      h16x8 pa0 = *(const h16x8*)(&sm.P[w][l15][(l4*8) ^ kswz]);
      h16x8 pa1 = *(const h16x8*)(&sm.P[w][l15][(32 + l4*8) ^ kswz]);
#pragma unroll
      for (int vc = 0; vc < 4; ++vc) {
        const int d = vc*16 + l15;
        h16x8 vb0 = *(const h16x8*)(&sm.Vt[cur][d][(l4*8) ^ kswz]);
        h16x8 vb1 = *(const h16x8*)(&sm.Vt[cur][d][(32 + l4*8) ^ kswz]);
        acc[vc] = __builtin_amdgcn_mfma_f32_16x16x32_f16(pa0, vb0, acc[vc], 0, 0, 0);
        acc[vc] = __builtin_amdgcn_mfma_f32_16x16x32_f16(pa1, vb1, acc[vc], 0, 0, 0);
      }
    }

    cls = clsN;
    if (kt < 31) __syncthreads();   // single barrier per tile (dbuf makes it sufficient)
  }

  // ---- fold clip masses + interior lsum over the 16-lane row group ----
#pragma unroll
  for (int j = 0; j < 4; ++j) {
    for (int mask = 1; mask < 16; mask <<= 1) {
      c0[j]   += __shfl_xor(c0[j],   mask);
      c192[j] += __shfl_xor(c192[j], mask);
      lsum[j] += __shfl_xor(lsum[j], mask);
    }
    lsum[j] += c0[j] + c192[j];     // total softmax denominator
  }
  if (l15 == 0) {
#pragma unroll
    for (int j = 0; j < 4; ++j) {
      sm.attnRh[w*16 + l4*4 + j][0]   = (h16)c0[j];
      sm.attnRh[w*16 + l4*4 + j][192] = (h16)c192[j];
    }
  }
  // no barrier: attnRh rows are wave-local; LDS ops are in-order per wave

  // ---- w2 epilogue: acc += attnRh @ relv (7 k-blocks x 4 col-tiles MFMA) ----
#pragma unroll
  for (int kb6 = 0; kb6 < 7; ++kb6) {
    h16x8 pa = *(const h16x8*)(&sm.attnRh[w*16 + l15][kb6*32 + l4*8]);
#pragma unroll
    for (int vc = 0; vc < 4; ++vc) {
      h16x8 bf = *(const h16x8*)(relvh + ((size_t)((kb6*4 + vc)*64 + l))*8);
      acc[vc] = __builtin_amdgcn_mfma_f32_16x16x32_f16(pa, bf, acc[vc], 0, 0, 0);
    }
  }

  // ---- normalize + store x (f16) ----
  float inv[4];
#pragma unroll
  for (int j = 0; j < 4; ++j) inv[j] = 1.f / lsum[j];
#pragma unroll
  for (int vc = 0; vc < 4; ++vc) {
#pragma unroll
    for (int j = 0; j < 4; ++j) {
      const int row16 = l4*4 + j;
      const int col   = vc*16 + l15;
      xout[((size_t)(b*SEQ) + q0 + w*16 + row16) * HID + h*DH + col] =
          (h16)(acc[vc][j] * inv[j]);
    }
  }
}

// ---------------- K2: out = x @ Wo^T + bo ----------------
template<bool WH>
__global__ __launch_bounds__(256)
void out_proj(const h16* __restrict__ xh,
              const float* __restrict__ Wo,
              const h16* __restrict__ Woh,
              const float* __restrict__ bo,
              float* __restrict__ out)
{
  const int tid = (int)threadIdx.x;
  const int w = tid >> 6, l = tid & 63, l15 = l & 15, l4 = l >> 4;
  const int m0 = blockIdx.x * 64 + w * 16;
  const int n0 = blockIdx.y * 64;
  f32x4 acc[4] = {};
  const h16* arow = xh + (size_t)(m0 + l15) * HID + l4*8;
#pragma unroll
  for (int ks = 0; ks < 16; ++ks) {
    h16x8 a = *(const h16x8*)(arow + ks*32);
#pragma unroll
    for (int ct = 0; ct < 4; ++ct) {
      h16x8 bfrag;
      if constexpr (WH) {
        bfrag = *(const h16x8*)(Woh + (size_t)(n0 + ct*16 + l15) * HID + ks*32 + l4*8);
      } else {
        const float* wrow = Wo + (size_t)(n0 + ct*16 + l15) * HID + ks*32 + l4*8;
        bfrag = pack8(*(const float4*)wrow, *(const float4*)(wrow + 4));
      }
      acc[ct] = __builtin_amdgcn_mfma_f32_16x16x32_f16(a, bfrag, acc[ct], 0, 0, 0);
    }
  }
#pragma unroll
  for (int ct = 0; ct < 4; ++ct) {
    const int col = n0 + ct*16 + l15;
    const float bv = bo[col];
#pragma unroll
    for (int j = 0; j < 4; ++j)
      out[(size_t)(m0 + l4*4 + j) * HID + col] = acc[ct][j] + bv;
  }
}

extern "C" void kernel_launch(void* const* d_in, const int* in_sizes, int n_in,
                              void* d_out, int out_size, void* d_ws, size_t ws_size,
                              hipStream_t stream)
{
  const float* qkv  = (const float*)d_in[0];
  const float* relk = (const float*)d_in[1];
  const float* relv = (const float*)d_in[2];
  const float* Wo   = (const float*)d_in[3];
  const float* bo   = (const float*)d_in[4];
  float* out = (float*)d_out;

  const size_t sz_xh    = (size_t)4*SEQ*HID*2;            //  8.39 MB
  const size_t sz_gproj = (size_t)4*NHEAD*SEQ*GPS*2;      // 25.69 MB
  const size_t sz_woh   = (size_t)HID*HID*2;              //  0.52 MB
  const size_t sz_relvh = (size_t)28*64*8*2;              // 28672 B

  h16* xh = (h16*)d_ws;

  const size_t off_gproj = sz_xh;
  const size_t off_woh   = off_gproj + sz_gproj;
  const size_t off_relvh = off_woh + sz_woh;
  const size_t need      = off_relvh + sz_relvh;

  if (ws_size >= need) {
    h16* gproj  = (h16*)((char*)d_ws + off_gproj);
    h16* woh    = (h16*)((char*)d_ws + off_woh);
    h16* relvh  = (h16*)((char*)d_ws + off_relvh);
    relv_pack<<<dim3(28), 64, 0, stream>>>(relv, relvh);
    proj_gemm<<<dim3(SEQ/64, NHEAD, 4), 256, 0, stream>>>(qkv, relk, gproj);
    wo_convert<<<dim3(HID*HID/4/256), 256, 0, stream>>>(Wo, woh);
    attn_fused<true><<<dim3(1024), 256, 0, stream>>>(qkv, relk, relv, gproj, relvh, xh);
    out_proj<true><<<dim3((4*SEQ)/64, HID/64), 256, 0, stream>>>(xh, Wo, woh, bo, out);
  } else {
    h16* relvh = (h16*)((char*)d_ws + sz_xh);   // fallback layout: xh | relvh
    relv_pack<<<dim3(28), 64, 0, stream>>>(relv, relvh);
    attn_fused<false><<<dim3(1024), 256, 0, stream>>>(qkv, relk, relv, nullptr, relvh, xh);
    out_proj<false><<<dim3((4*SEQ)/64, HID/64), 256, 0, stream>>>(xh, Wo, nullptr, bo, out);
  }
}